// Round 3
// baseline (79.002 us; speedup 1.0000x reference)
//
#include <hip/hip_runtime.h>

// ============================================================================
// PC-DONN collapse (validated rounds 1-2, absmax 0.0):
//   |H|==1 and |exp(i*phase)|==1; FFT pairs obey Parseval => sum|field|^2 is
//   exactly invariant through the whole propagation chain. Hence
//       out[b] = (1/M) * sum_p x_in[b,p]^2 * sum_m |T_m[p]|^2
//   with T_m = fftshift(IDFT2_unnorm(C_m * G)), G = sqrt(p_v + 1e-12).
//
// Round 3: round-2 profile shows ~10 us per graph node of launch overhead
// dominating (~40 us of overhead for ~10 us of memory-roofline work).
// Collapse 4 kernels -> 2:
//   KA: row FFTs -> transposed mid; m==0 blocks also zero Wsh + counter.
//   KB: col FFTs (2 screens/block), |T|^2 accumulated in registers, then
//       atomicAdd into shifted/transposed Wsh; decoupled "last 32 blocks"
//       tail (threadfence + counter + acquire spin) computes out[b] directly.
// ============================================================================

struct cplx { float x, y; };
__device__ __forceinline__ cplx cadd(cplx a, cplx b){ return {a.x+b.x, a.y+b.y}; }
__device__ __forceinline__ cplx csub(cplx a, cplx b){ return {a.x-b.x, a.y-b.y}; }
__device__ __forceinline__ cplx cmul(cplx a, cplx b){ return {a.x*b.x - a.y*b.y, a.x*b.y + a.y*b.x}; }
__device__ __forceinline__ cplx cmuli(cplx a){ return {-a.y, a.x}; }   // * (+i): inverse-FFT sign

__device__ __forceinline__ void idft4(cplx&A,cplx&B,cplx&C,cplx&D){
    cplx e0=cadd(A,C), e1=csub(A,C), o0=cadd(B,D), o1=csub(B,D);
    cplx i1 = cmuli(o1);
    A=cadd(e0,o0); B=cadd(e1,i1); C=csub(e0,o0); D=csub(e1,i1);
}
__device__ __forceinline__ void idft8(cplx a[8]){
    cplx e0=a[0],e1=a[2],e2=a[4],e3=a[6];
    cplx o0=a[1],o1=a[3],o2=a[5],o3=a[7];
    idft4(e0,e1,e2,e3); idft4(o0,o1,o2,o3);
    const float Ch = 0.70710678118654752f;
    cplx t1 = cmul(o1, cplx{ Ch, Ch});
    cplx t2 = cmuli(o2);
    cplx t3 = cmul(o3, cplx{-Ch, Ch});
    a[0]=cadd(e0,o0); a[4]=csub(e0,o0);
    a[1]=cadd(e1,t1); a[5]=csub(e1,t1);
    a[2]=cadd(e2,t2); a[6]=csub(e2,t2);
    a[3]=cadd(e3,t3); a[7]=csub(e3,t3);
}
__device__ __forceinline__ void idft16(cplx a[16]){
    cplx e[8]={a[0],a[2],a[4],a[6],a[8],a[10],a[12],a[14]};
    cplx o[8]={a[1],a[3],a[5],a[7],a[9],a[11],a[13],a[15]};
    idft8(e); idft8(o);
    const float Ch=0.70710678118654752f, c1=0.92387953251128674f, s1=0.38268343236508977f;
    const cplx w[8]={{1.f,0.f},{c1,s1},{Ch,Ch},{s1,c1},{0.f,1.f},{-s1,c1},{-Ch,Ch},{-c1,s1}};
    #pragma unroll
    for(int n=0;n<8;++n){ cplx t=cmul(o[n],w[n]); a[n]=cadd(e[n],t); a[n+8]=csub(e[n],t); }
}

#define LDSP 130   // padded row stride (cplx)
#define NR   16    // rows (or cols) per block-tile
#define MG   2     // screens per KB block

// In-place FFT-128 of NR rows in fld. 128 threads: r=tid>>3 row, t=tid&7.
__device__ __forceinline__ void fft128_rows(cplx* fld, const cplx* tw, int tid)
{
    const int r = tid >> 3, t = tid & 7;
    cplx* row = fld + r * LDSP;
    {   cplx a[16];
        #pragma unroll
        for (int k1 = 0; k1 < 16; ++k1) a[k1] = row[t + 8*k1];
        idft16(a);
        #pragma unroll
        for (int n1 = 0; n1 < 16; ++n1) row[t + 8*n1] = cmul(a[n1], tw[(n1*t) & 127]);
    }
    __syncthreads();
    {   cplx b0[8], b1[8];
        #pragma unroll
        for (int k2 = 0; k2 < 8; ++k2) { b0[k2] = row[8*t + k2]; b1[k2] = row[8*(t+8) + k2]; }
        idft8(b0); idft8(b1);
        __syncthreads();
        #pragma unroll
        for (int n2 = 0; n2 < 8; ++n2) {
            row[ t      + 16*n2] = b0[n2];
            row[(t + 8) + 16*n2] = b1[n2];
        }
    }
    __syncthreads();
}

// KA: row FFTs of C*G -> transposed mid[m][c*128 + i]; m==0 blocks zero Wsh,
// block (0,0) zeroes the tail counter.
__global__ __launch_bounds__(128)
void rowfft_kernel(const float* __restrict__ c_noise, float2* __restrict__ mid,
                   float* __restrict__ Wsh, unsigned* __restrict__ counter)
{
    __shared__ cplx fld[NR * LDSP];
    __shared__ cplx tw[128];
    const int m   = blockIdx.x;
    const int rb  = blockIdx.y * NR;
    const int tid = threadIdx.x;

    if (m == 0) {                     // zero Wsh (8 blocks x 2048 floats)
        float4* wz = (float4*)Wsh;
        #pragma unroll
        for (int k = 0; k < 4; ++k)
            wz[blockIdx.y*512 + k*128 + tid] = {0.f, 0.f, 0.f, 0.f};
        if (blockIdx.y == 0 && tid == 0) *counter = 0u;
    }

    {   float s, c;
        sincosf((float)tid * (float)(2.0 * M_PI / 128.0), &s, &c);
        tw[tid] = { c, s };
    }

    const float DF = 976.5625f;                  // 1/(N*DX)
    const float Ac = 2.5132741228718345e-7f;     // 2*pi*L^2
    const float Bc = 7.8956835208714865e-7f;     // 2*pi^2*L^2
    #pragma unroll
    for (int it = 0; it < NR; ++it) {
        const int i = rb + it, j = tid;
        float fi = (float)(((i+64)&127) - 64) * DF;
        float fj = (float)(((j+64)&127) - 64) * DF;
        float G  = sqrtf(Ac * expf(-Bc * (fi*fi + fj*fj)) + 1e-12f);
        float2 cv = ((const float2*)c_noise)[(size_t)m*16384 + i*128 + j];
        fld[it*LDSP + j] = { cv.x * G, cv.y * G };
    }
    __syncthreads();

    fft128_rows(fld, tw, tid);

    const int c = tid;                 // transposed store: 128 B per thread-pair
    float4* dst4 = (float4*)(mid + (size_t)m*16384 + (size_t)c*128 + rb);
    #pragma unroll
    for (int r2 = 0; r2 < NR/2; ++r2) {
        cplx v0 = fld[(2*r2  )*LDSP + c];
        cplx v1 = fld[(2*r2+1)*LDSP + c];
        dst4[r2] = { v0.x, v0.y, v1.x, v1.y };
    }
}

// KB: col FFTs for MG screens per block; atomicAdd |T|^2 into shifted
// Wsh[(r^64)*128 + (c^64)]; last-32-blocks tail computes out[b].
__global__ __launch_bounds__(128)
void colfft_fused_kernel(const float2* __restrict__ mid, float* __restrict__ Wsh,
                         unsigned* __restrict__ counter,
                         const float* __restrict__ x, float* __restrict__ out,
                         int M, int B)
{
    __shared__ cplx fld[NR * LDSP];
    __shared__ cplx tw[128];
    __shared__ unsigned s_old;
    __shared__ float part[2];
    const int g   = blockIdx.x;          // screen pair
    const int cb  = blockIdx.y * NR;     // column tile base
    const int tid = threadIdx.x;

    {   float s, c;
        sincosf((float)tid * (float)(2.0 * M_PI / 128.0), &s, &c);
        tw[tid] = { c, s };
    }

    float acc[NR];
    #pragma unroll
    for (int it = 0; it < NR; ++it) acc[it] = 0.f;

    for (int mm = 0; mm < MG; ++mm) {
        const int m = g*MG + mm;
        #pragma unroll
        for (int it = 0; it < NR; ++it) {
            float2 v = mid[(size_t)m*16384 + (size_t)(cb + it)*128 + tid];
            fld[it*LDSP + tid] = { v.x, v.y };
        }
        __syncthreads();
        fft128_rows(fld, tw, tid);
        #pragma unroll
        for (int it = 0; it < NR; ++it) {
            cplx v = fld[it*LDSP + tid];
            acc[it] += v.x*v.x + v.y*v.y;
        }
        __syncthreads();                 // reuse fld for next screen
    }

    // scatter-accumulate into shifted/transposed W: lane tid -> row tid^64,
    // 16 consecutive columns (cb^64 .. cb^64+15) since cb is 16-aligned.
    {
        float* wrow = Wsh + ((tid ^ 64) << 7) + ((cb ^ 64) & 127) - ((cb & 64) ? 0 : 0);
        const int c0 = (cb ^ 64);        // (cb+it)^64 == (cb^64)+it for it<16
        #pragma unroll
        for (int it = 0; it < NR; ++it)
            atomicAdd(&Wsh[((tid ^ 64) << 7) | (c0 + it)], acc[it]);
        (void)wrow;
    }

    // ---- decoupled tail: last 32 blocks compute out[b] ----
    __threadfence();                     // release Wsh atomics to device scope
    __syncthreads();
    const unsigned total = gridDim.x * gridDim.y;
    if (tid == 0)
        s_old = __hip_atomic_fetch_add(counter, 1u, __ATOMIC_ACQ_REL,
                                       __HIP_MEMORY_SCOPE_AGENT);
    __syncthreads();
    const unsigned old = s_old;          // block-uniform

    if (old + 32 >= total) {
        const int b = (int)(total - 1u - old);      // 0..31
        if (b < B) {
            while (__hip_atomic_load(counter, __ATOMIC_ACQUIRE,
                                     __HIP_MEMORY_SCOPE_AGENT) < total)
                __builtin_amdgcn_s_sleep(1);
            const float4* x4 = (const float4*)(x + (size_t)b * 16384);
            const float4* w4 = (const float4*)Wsh;
            float a = 0.f;
            #pragma unroll 4
            for (int k = tid; k < 4096; k += 128) {
                float4 xv = x4[k], wv = w4[k];
                a = fmaf(xv.x*xv.x, wv.x, a);
                a = fmaf(xv.y*xv.y, wv.y, a);
                a = fmaf(xv.z*xv.z, wv.z, a);
                a = fmaf(xv.w*xv.w, wv.w, a);
            }
            #pragma unroll
            for (int off = 32; off > 0; off >>= 1) a += __shfl_down(a, off);
            if ((tid & 63) == 0) part[tid >> 6] = a;
            __syncthreads();
            if (tid == 0) out[b] = (part[0] + part[1]) / (float)M;
        }
    }
}

extern "C" void kernel_launch(void* const* d_in, const int* in_sizes, int n_in,
                              void* d_out, int out_size, void* d_ws, size_t ws_size,
                              hipStream_t stream)
{
    (void)n_in; (void)ws_size;
    const float* x_in    = (const float*)d_in[0];
    // d_in[1] (phases) provably does not affect the output (|exp(i*phase)|=1).
    const float* c_noise = (const float*)d_in[2];

    const int M = in_sizes[2] / (128*128*2);   // 100
    const int B = out_size;                    // 32

    float2*   mid     = (float2*)d_ws;                               // M*16384*8 B
    float*    Wsh     = (float*)((char*)d_ws + (size_t)M*16384*8);   // 64 KB
    unsigned* counter = (unsigned*)((char*)Wsh + 16384*4);           // 4 B

    rowfft_kernel      <<<dim3(M, 8),    dim3(128), 0, stream>>>(c_noise, mid, Wsh, counter);
    colfft_fused_kernel<<<dim3(M/MG, 8), dim3(128), 0, stream>>>(mid, Wsh, counter,
                                                                 x_in, (float*)d_out, M, B);
}

// Round 4
// 46.720 us; speedup vs baseline: 1.6910x; 1.6910x over previous
//
#include <hip/hip_runtime.h>

// ============================================================================
// PC-DONN collapse (validated rounds 1-3, absmax 0.0):
//   |H|==1 and |exp(i*phase)|==1; FFT pairs obey Parseval => sum|field|^2 is
//   exactly invariant through the whole propagation chain. Hence
//       out[b] = (1/M) * sum_p x_in[b,p]^2 * sum_m |T_m[p]|^2
//   with T_m = fftshift(IDFT2_unnorm(C_m * G)), G = sqrt(p_v + 1e-12).
//
// Round 4: round-3's fused kernel spent 67 us at 1.5% VALUBusy / 6% HBM --
// the DIY grid sync (819K Wsh atomics + per-block threadfence + 32-block
// spin) was the cost, not the FFTs. Remove it by swapping the sums:
//   out[b] = (1/M) sum_g [ sum_p x^2[b,p] * (sum_{m in g} |T_m[p]|^2) ]
// Each colfft block (group g of MG screens x 16-col tile) dots its local
// acc[16] against x^2 for all B batches and does ONE atomicAdd per (block,b)
// -- 6400 total, no fences, no spins. K1 zeroes out[] each call.
//   K1: row FFTs of C*G -> transposed mid[m][c*128+i]   (800 blocks)
//   K2: col FFTs (MG=4 screens/block), |T|^2 acc in regs, dot with x^2,
//       wave-reduce, atomicAdd out[b]                   (200 blocks)
// ============================================================================

struct cplx { float x, y; };
__device__ __forceinline__ cplx cadd(cplx a, cplx b){ return {a.x+b.x, a.y+b.y}; }
__device__ __forceinline__ cplx csub(cplx a, cplx b){ return {a.x-b.x, a.y-b.y}; }
__device__ __forceinline__ cplx cmul(cplx a, cplx b){ return {a.x*b.x - a.y*b.y, a.x*b.y + a.y*b.x}; }
__device__ __forceinline__ cplx cmuli(cplx a){ return {-a.y, a.x}; }   // * (+i): inverse-FFT sign

__device__ __forceinline__ void idft4(cplx&A,cplx&B,cplx&C,cplx&D){
    cplx e0=cadd(A,C), e1=csub(A,C), o0=cadd(B,D), o1=csub(B,D);
    cplx i1 = cmuli(o1);
    A=cadd(e0,o0); B=cadd(e1,i1); C=csub(e0,o0); D=csub(e1,i1);
}
__device__ __forceinline__ void idft8(cplx a[8]){
    cplx e0=a[0],e1=a[2],e2=a[4],e3=a[6];
    cplx o0=a[1],o1=a[3],o2=a[5],o3=a[7];
    idft4(e0,e1,e2,e3); idft4(o0,o1,o2,o3);
    const float Ch = 0.70710678118654752f;
    cplx t1 = cmul(o1, cplx{ Ch, Ch});
    cplx t2 = cmuli(o2);
    cplx t3 = cmul(o3, cplx{-Ch, Ch});
    a[0]=cadd(e0,o0); a[4]=csub(e0,o0);
    a[1]=cadd(e1,t1); a[5]=csub(e1,t1);
    a[2]=cadd(e2,t2); a[6]=csub(e2,t2);
    a[3]=cadd(e3,t3); a[7]=csub(e3,t3);
}
__device__ __forceinline__ void idft16(cplx a[16]){
    cplx e[8]={a[0],a[2],a[4],a[6],a[8],a[10],a[12],a[14]};
    cplx o[8]={a[1],a[3],a[5],a[7],a[9],a[11],a[13],a[15]};
    idft8(e); idft8(o);
    const float Ch=0.70710678118654752f, c1=0.92387953251128674f, s1=0.38268343236508977f;
    const cplx w[8]={{1.f,0.f},{c1,s1},{Ch,Ch},{s1,c1},{0.f,1.f},{-s1,c1},{-Ch,Ch},{-c1,s1}};
    #pragma unroll
    for(int n=0;n<8;++n){ cplx t=cmul(o[n],w[n]); a[n]=cadd(e[n],t); a[n+8]=csub(e[n],t); }
}

#define LDSP 130   // padded row stride (cplx)
#define NR   16    // rows (or cols) per block-tile
#define MG   4     // screens per K2 block

// In-place FFT-128 of NR rows in fld. 128 threads: r=tid>>3 row, t=tid&7.
__device__ __forceinline__ void fft128_rows(cplx* fld, const cplx* tw, int tid)
{
    const int r = tid >> 3, t = tid & 7;
    cplx* row = fld + r * LDSP;
    {   cplx a[16];
        #pragma unroll
        for (int k1 = 0; k1 < 16; ++k1) a[k1] = row[t + 8*k1];
        idft16(a);
        #pragma unroll
        for (int n1 = 0; n1 < 16; ++n1) row[t + 8*n1] = cmul(a[n1], tw[(n1*t) & 127]);
    }
    __syncthreads();
    {   cplx b0[8], b1[8];
        #pragma unroll
        for (int k2 = 0; k2 < 8; ++k2) { b0[k2] = row[8*t + k2]; b1[k2] = row[8*(t+8) + k2]; }
        idft8(b0); idft8(b1);
        __syncthreads();
        #pragma unroll
        for (int n2 = 0; n2 < 8; ++n2) {
            row[ t      + 16*n2] = b0[n2];
            row[(t + 8) + 16*n2] = b1[n2];
        }
    }
    __syncthreads();
}

// K1: row FFTs of C*G -> transposed mid[m][c*128 + i]; block (0,0) zeroes out[].
__global__ __launch_bounds__(128)
void rowfft_kernel(const float* __restrict__ c_noise, float2* __restrict__ mid,
                   float* __restrict__ out, int B)
{
    __shared__ cplx fld[NR * LDSP];
    __shared__ cplx tw[128];
    const int m   = blockIdx.x;
    const int rb  = blockIdx.y * NR;
    const int tid = threadIdx.x;

    if (m == 0 && blockIdx.y == 0 && tid < B) out[tid] = 0.f;

    {   float s, c;
        sincosf((float)tid * (float)(2.0 * M_PI / 128.0), &s, &c);
        tw[tid] = { c, s };
    }

    const float DF = 976.5625f;                  // 1/(N*DX)
    const float Ac = 2.5132741228718345e-7f;     // 2*pi*L^2
    const float Bc = 7.8956835208714865e-7f;     // 2*pi^2*L^2
    #pragma unroll
    for (int it = 0; it < NR; ++it) {
        const int i = rb + it, j = tid;
        float fi = (float)(((i+64)&127) - 64) * DF;
        float fj = (float)(((j+64)&127) - 64) * DF;
        float G  = sqrtf(Ac * expf(-Bc * (fi*fi + fj*fj)) + 1e-12f);
        float2 cv = ((const float2*)c_noise)[(size_t)m*16384 + i*128 + j];
        fld[it*LDSP + j] = { cv.x * G, cv.y * G };
    }
    __syncthreads();

    fft128_rows(fld, tw, tid);

    const int c = tid;                 // transposed store: 128 B per thread-pair
    float4* dst4 = (float4*)(mid + (size_t)m*16384 + (size_t)c*128 + rb);
    #pragma unroll
    for (int r2 = 0; r2 < NR/2; ++r2) {
        cplx v0 = fld[(2*r2  )*LDSP + c];
        cplx v1 = fld[(2*r2+1)*LDSP + c];
        dst4[r2] = { v0.x, v0.y, v1.x, v1.y };
    }
}

// K2: col FFTs for MG screens; acc |T|^2 in regs; dot with x^2 for all b;
// one atomicAdd per (block, b).
__global__ __launch_bounds__(128)
void colfft_dot_kernel(const float2* __restrict__ mid,
                       const float* __restrict__ x,
                       float* __restrict__ out, int M, int B)
{
    __shared__ cplx fld[NR * LDSP];
    __shared__ cplx tw[128];
    __shared__ float part[2][32];
    const int g   = blockIdx.x;          // screen group
    const int cb  = blockIdx.y * NR;     // column tile base (16-aligned)
    const int tid = threadIdx.x;

    {   float s, c;
        sincosf((float)tid * (float)(2.0 * M_PI / 128.0), &s, &c);
        tw[tid] = { c, s };
    }

    float acc[NR];
    #pragma unroll
    for (int it = 0; it < NR; ++it) acc[it] = 0.f;

    for (int mm = 0; mm < MG; ++mm) {
        const int m = g*MG + mm;
        if (m < M) {                      // block-uniform branch
            #pragma unroll
            for (int it = 0; it < NR; ++it) {
                float2 v = mid[(size_t)m*16384 + (size_t)(cb + it)*128 + tid];
                fld[it*LDSP + tid] = { v.x, v.y };
            }
            __syncthreads();
            fft128_rows(fld, tw, tid);    // ends with __syncthreads
            #pragma unroll
            for (int it = 0; it < NR; ++it) {
                cplx v = fld[it*LDSP + tid];
                acc[it] += v.x*v.x + v.y*v.y;
            }
            __syncthreads();              // fld reused next screen
        }
    }

    // acc[it] = sum_m |T[row=tid][col=cb+it]|^2 (pre-shift indices).
    // Shifted pixel: row rr = tid^64, cols c0..c0+15 with c0 = cb^64
    // ((cb+it)^64 == (cb^64)+it since cb is 16-aligned and it<16).
    const int rr   = tid ^ 64;
    const int c0   = cb ^ 64;
    const int lane = tid & 63, w = tid >> 6;

    for (int b = 0; b < B; ++b) {
        const float4* x4 = (const float4*)(x + (size_t)b*16384 + rr*128 + c0);
        float s = 0.f;
        #pragma unroll
        for (int q = 0; q < 4; ++q) {
            float4 xv = x4[q];
            s = fmaf(xv.x*xv.x, acc[4*q+0], s);
            s = fmaf(xv.y*xv.y, acc[4*q+1], s);
            s = fmaf(xv.z*xv.z, acc[4*q+2], s);
            s = fmaf(xv.w*xv.w, acc[4*q+3], s);
        }
        #pragma unroll
        for (int off = 32; off > 0; off >>= 1) s += __shfl_down(s, off);
        if (lane == 0) part[w][b & 31] = s;
    }
    __syncthreads();
    if (tid < B && tid < 32)
        atomicAdd(&out[tid], (part[0][tid] + part[1][tid]) / (float)M);
}

extern "C" void kernel_launch(void* const* d_in, const int* in_sizes, int n_in,
                              void* d_out, int out_size, void* d_ws, size_t ws_size,
                              hipStream_t stream)
{
    (void)n_in; (void)ws_size;
    const float* x_in    = (const float*)d_in[0];
    // d_in[1] (phases) provably does not affect the output (|exp(i*phase)|=1).
    const float* c_noise = (const float*)d_in[2];

    const int M = in_sizes[2] / (128*128*2);   // 100
    const int B = out_size;                    // 32

    float2* mid = (float2*)d_ws;               // M*16384*8 B = 13.1 MB

    const int G = (M + MG - 1) / MG;           // 25 screen groups

    rowfft_kernel    <<<dim3(M, 8), dim3(128), 0, stream>>>(c_noise, mid,
                                                            (float*)d_out, B);
    colfft_dot_kernel<<<dim3(G, 8), dim3(128), 0, stream>>>(mid, x_in,
                                                            (float*)d_out, M, B);
}

// Round 5
// 40.787 us; speedup vs baseline: 1.9369x; 1.1455x over previous
//
#include <hip/hip_runtime.h>

// ============================================================================
// PC-DONN collapse (validated rounds 1-4, absmax 0.0):
//   |H|==1 and |exp(i*phase)|==1; FFT pairs obey Parseval => sum|field|^2 is
//   exactly invariant through the whole propagation chain. Hence
//       out[b] = (1/M) * sum_p x_in[b,p]^2 * sum_m |T_m[p]|^2
//   with T_m = fftshift(IDFT2_unnorm(C_m * G)), G = sqrt(p_v + 1e-12).
//
// Round 5: round-4's colfft_dot ran 39.5us at 3.8% VALU / 3.6% occupancy --
// latency-serial: 200 blocks x 2 waves (0.78 blocks/CU), each serially
// chaining 4 screens x {global->LDS, 3-barrier FFT} + a 32-batch dot.
// Fix: process the 4 screens CONCURRENTLY in one 512-thread block (4 groups
// of 128, one 16x130 LDS slab each; fft128_rows already spans 64 rows at
// 512 threads). Then reduce |T|^2 over the 4 slabs into Wt[16][128] in LDS
// and let all 8 waves do the 32-batch dot (1 float4 of x per thread per b,
// L2-resident) -> wave reduce -> part[8][32] -> one atomicAdd per (block,b).
// Per-block serial chain ~4x shorter; grid stays 200 blocks (8 waves each).
// ============================================================================

struct cplx { float x, y; };
__device__ __forceinline__ cplx cadd(cplx a, cplx b){ return {a.x+b.x, a.y+b.y}; }
__device__ __forceinline__ cplx csub(cplx a, cplx b){ return {a.x-b.x, a.y-b.y}; }
__device__ __forceinline__ cplx cmul(cplx a, cplx b){ return {a.x*b.x - a.y*b.y, a.x*b.y + a.y*b.x}; }
__device__ __forceinline__ cplx cmuli(cplx a){ return {-a.y, a.x}; }   // * (+i): inverse-FFT sign

__device__ __forceinline__ void idft4(cplx&A,cplx&B,cplx&C,cplx&D){
    cplx e0=cadd(A,C), e1=csub(A,C), o0=cadd(B,D), o1=csub(B,D);
    cplx i1 = cmuli(o1);
    A=cadd(e0,o0); B=cadd(e1,i1); C=csub(e0,o0); D=csub(e1,i1);
}
__device__ __forceinline__ void idft8(cplx a[8]){
    cplx e0=a[0],e1=a[2],e2=a[4],e3=a[6];
    cplx o0=a[1],o1=a[3],o2=a[5],o3=a[7];
    idft4(e0,e1,e2,e3); idft4(o0,o1,o2,o3);
    const float Ch = 0.70710678118654752f;
    cplx t1 = cmul(o1, cplx{ Ch, Ch});
    cplx t2 = cmuli(o2);
    cplx t3 = cmul(o3, cplx{-Ch, Ch});
    a[0]=cadd(e0,o0); a[4]=csub(e0,o0);
    a[1]=cadd(e1,t1); a[5]=csub(e1,t1);
    a[2]=cadd(e2,t2); a[6]=csub(e2,t2);
    a[3]=cadd(e3,t3); a[7]=csub(e3,t3);
}
__device__ __forceinline__ void idft16(cplx a[16]){
    cplx e[8]={a[0],a[2],a[4],a[6],a[8],a[10],a[12],a[14]};
    cplx o[8]={a[1],a[3],a[5],a[7],a[9],a[11],a[13],a[15]};
    idft8(e); idft8(o);
    const float Ch=0.70710678118654752f, c1=0.92387953251128674f, s1=0.38268343236508977f;
    const cplx w[8]={{1.f,0.f},{c1,s1},{Ch,Ch},{s1,c1},{0.f,1.f},{-s1,c1},{-Ch,Ch},{-c1,s1}};
    #pragma unroll
    for(int n=0;n<8;++n){ cplx t=cmul(o[n],w[n]); a[n]=cadd(e[n],t); a[n+8]=csub(e[n],t); }
}

#define LDSP 130   // padded row stride (cplx)
#define NR   16    // rows (or cols) per tile
#define MG   4     // screens per K2 block (processed concurrently; M%MG==0)

// In-place FFT-128 of (blockDim.x/8) rows in fld. r=tid>>3 row, t=tid&7.
__device__ __forceinline__ void fft128_rows(cplx* fld, const cplx* tw, int tid)
{
    const int r = tid >> 3, t = tid & 7;
    cplx* row = fld + r * LDSP;
    {   cplx a[16];
        #pragma unroll
        for (int k1 = 0; k1 < 16; ++k1) a[k1] = row[t + 8*k1];
        idft16(a);
        #pragma unroll
        for (int n1 = 0; n1 < 16; ++n1) row[t + 8*n1] = cmul(a[n1], tw[(n1*t) & 127]);
    }
    __syncthreads();
    {   cplx b0[8], b1[8];
        #pragma unroll
        for (int k2 = 0; k2 < 8; ++k2) { b0[k2] = row[8*t + k2]; b1[k2] = row[8*(t+8) + k2]; }
        idft8(b0); idft8(b1);
        __syncthreads();
        #pragma unroll
        for (int n2 = 0; n2 < 8; ++n2) {
            row[ t      + 16*n2] = b0[n2];
            row[(t + 8) + 16*n2] = b1[n2];
        }
    }
    __syncthreads();
}

// K1: row FFTs of C*G -> transposed mid[m][c*128 + i]; block (0,0) zeroes out[].
__global__ __launch_bounds__(128)
void rowfft_kernel(const float* __restrict__ c_noise, float2* __restrict__ mid,
                   float* __restrict__ out, int B)
{
    __shared__ cplx fld[NR * LDSP];
    __shared__ cplx tw[128];
    const int m   = blockIdx.x;
    const int rb  = blockIdx.y * NR;
    const int tid = threadIdx.x;

    if (m == 0 && blockIdx.y == 0 && tid < B) out[tid] = 0.f;

    {   float s, c;
        sincosf((float)tid * (float)(2.0 * M_PI / 128.0), &s, &c);
        tw[tid] = { c, s };
    }

    const float DF = 976.5625f;                  // 1/(N*DX)
    const float Ac = 2.5132741228718345e-7f;     // 2*pi*L^2
    const float Bc = 7.8956835208714865e-7f;     // 2*pi^2*L^2
    #pragma unroll
    for (int it = 0; it < NR; ++it) {
        const int i = rb + it, j = tid;
        float fi = (float)(((i+64)&127) - 64) * DF;
        float fj = (float)(((j+64)&127) - 64) * DF;
        float G  = sqrtf(Ac * expf(-Bc * (fi*fi + fj*fj)) + 1e-12f);
        float2 cv = ((const float2*)c_noise)[(size_t)m*16384 + i*128 + j];
        fld[it*LDSP + j] = { cv.x * G, cv.y * G };
    }
    __syncthreads();

    fft128_rows(fld, tw, tid);

    const int c = tid;                 // transposed store: 128 B per thread
    float4* dst4 = (float4*)(mid + (size_t)m*16384 + (size_t)c*128 + rb);
    #pragma unroll
    for (int r2 = 0; r2 < NR/2; ++r2) {
        cplx v0 = fld[(2*r2  )*LDSP + c];
        cplx v1 = fld[(2*r2+1)*LDSP + c];
        dst4[r2] = { v0.x, v0.y, v1.x, v1.y };
    }
}

// K2: 4 screens concurrently (one 128-thread group each), |T|^2 reduced in
// LDS to Wt, all 8 waves dot vs x^2 for 32 batches, atomicAdd out[b].
__global__ __launch_bounds__(512)
void colfft_dot_kernel(const float2* __restrict__ mid,
                       const float* __restrict__ x,
                       float* __restrict__ out, int M, int B)
{
    __shared__ cplx  fld[MG * NR * LDSP];     // 4 slabs of 16 rows -> 66.56 KB
    __shared__ cplx  tw[128];
    __shared__ float Wt[NR * 128];            // reduced |T|^2 tile [it][row]
    __shared__ float part[8][32];
    const int g   = blockIdx.x;               // screen group (MG screens)
    const int cb  = blockIdx.y * NR;          // column tile base (16-aligned)
    const int tid = threadIdx.x;
    const int grp = tid >> 7;                 // screen-group 0..3
    const int lt  = tid & 127;                // lane within group

    if (tid < 128) {
        float s, c;
        sincosf((float)tid * (float)(2.0 * M_PI / 128.0), &s, &c);
        tw[tid] = { c, s };
    }

    // load: group grp loads screen m's 16-column tile into its slab
    {
        const int m = g*MG + grp;             // M % MG == 0 (100 % 4)
        #pragma unroll
        for (int it = 0; it < NR; ++it) {
            float2 v = mid[(size_t)m*16384 + (size_t)(cb + it)*128 + lt];
            fld[(grp*NR + it)*LDSP + lt] = { v.x, v.y };
        }
    }
    __syncthreads();

    fft128_rows(fld, tw, tid);                // 64 rows across 4 slabs at once

    // |T|^2 in place (as .x), then reduce the 4 slabs into Wt
    #pragma unroll
    for (int it = 0; it < NR; ++it) {
        cplx v = fld[(grp*NR + it)*LDSP + lt];
        fld[(grp*NR + it)*LDSP + lt].x = v.x*v.x + v.y*v.y;
    }
    __syncthreads();
    #pragma unroll
    for (int k = 0; k < 4; ++k) {
        int p  = k*512 + tid;                 // 0..2047
        int it = p >> 7, r = p & 127;
        Wt[p] = fld[(0*NR + it)*LDSP + r].x + fld[(1*NR + it)*LDSP + r].x
              + fld[(2*NR + it)*LDSP + r].x + fld[(3*NR + it)*LDSP + r].x;
    }
    __syncthreads();

    // dot vs x^2: shifted pixel (row lt^64, cols (cb^64)+grp*4 .. +3).
    // thread (grp,lt): one float4 of x per b; Wt reads conflict-free.
    const int rr = lt ^ 64;
    const int c0 = cb ^ 64;
    const int lane = tid & 63, w = tid >> 6;

    for (int b = 0; b < B; ++b) {
        const float4* x4 = (const float4*)(x + (size_t)b*16384 + rr*128 + c0 + grp*4);
        float4 xv = x4[0];
        float sv;
        sv = xv.x*xv.x * Wt[(grp*4 + 0)*128 + lt];
        sv = fmaf(xv.y*xv.y, Wt[(grp*4 + 1)*128 + lt], sv);
        sv = fmaf(xv.z*xv.z, Wt[(grp*4 + 2)*128 + lt], sv);
        sv = fmaf(xv.w*xv.w, Wt[(grp*4 + 3)*128 + lt], sv);
        #pragma unroll
        for (int off = 32; off > 0; off >>= 1) sv += __shfl_down(sv, off);
        if (lane == 0) part[w][b] = sv;
    }
    __syncthreads();
    if (tid < B && tid < 32) {
        float t = 0.f;
        #pragma unroll
        for (int ww = 0; ww < 8; ++ww) t += part[ww][tid];
        atomicAdd(&out[tid], t / (float)M);
    }
}

extern "C" void kernel_launch(void* const* d_in, const int* in_sizes, int n_in,
                              void* d_out, int out_size, void* d_ws, size_t ws_size,
                              hipStream_t stream)
{
    (void)n_in; (void)ws_size;
    const float* x_in    = (const float*)d_in[0];
    // d_in[1] (phases) provably does not affect the output (|exp(i*phase)|=1).
    const float* c_noise = (const float*)d_in[2];

    const int M = in_sizes[2] / (128*128*2);   // 100 (M % MG == 0)
    const int B = out_size;                    // 32

    float2* mid = (float2*)d_ws;               // M*16384*8 B = 13.1 MB

    const int G = M / MG;                      // 25 screen groups

    rowfft_kernel    <<<dim3(M, 8), dim3(128), 0, stream>>>(c_noise, mid,
                                                            (float*)d_out, B);
    colfft_dot_kernel<<<dim3(G, 8), dim3(512), 0, stream>>>(mid, x_in,
                                                            (float*)d_out, M, B);
}